// Round 7
// baseline (360.690 us; speedup 1.0000x reference)
//
#include <hip/hip_runtime.h>

typedef _Float16 f16;
typedef _Float16 f16x8 __attribute__((ext_vector_type(8)));
typedef _Float16 f16x4 __attribute__((ext_vector_type(4)));
typedef float    f32x4 __attribute__((ext_vector_type(4)));
typedef unsigned int u32;
typedef u32 u32x2 __attribute__((ext_vector_type(2)));
typedef u32 u32x4 __attribute__((ext_vector_type(4)));
typedef unsigned short ush;

#define CC 256
#define NN 4096
#define BB 4
#define RSC 17          // combine buffer stride (f32)

union Frag8 { u32x4 u4; f16x8 f; };
union Frag4 { u32x2 u2; f16x4 f; };

static __device__ __forceinline__ u32 pkrtz(float a, float b) {
  auto t = __builtin_amdgcn_cvt_pkrtz(a, b);
  return __builtin_bit_cast(u32, t);
}
static __device__ __forceinline__ ush f2h(float x) {   // RNE
  f16 h = (f16)x;
  return __builtin_bit_cast(ush, h);
}

static __device__ __forceinline__ void gload16(const ush* g, ush* l) {
  __builtin_amdgcn_global_load_lds(
      (const __attribute__((address_space(1))) u32*)g,
      (__attribute__((address_space(3))) u32*)l, 16, 0, 0);
}

#define MFMA32(A, B, C) __builtin_amdgcn_mfma_f32_16x16x32_f16((A), (B), (C), 0, 0, 0)
#define MFMA16(A, B, C) __builtin_amdgcn_mfma_f32_16x16x16f16((A), (B), (C), 0, 0, 0)

// K1: M[c][cp] = sum_o w1[o,c]*w2[o,cp] ; g[cp] = sum_o b1[o]*w2[o,cp]
__global__ void k_prep(const float* __restrict__ w1, const float* __restrict__ w2,
                       const float* __restrict__ b1, float* __restrict__ M,
                       float* __restrict__ g) {
  const int c  = blockIdx.x;
  const int cp = threadIdx.x;
  float acc = 0.f;
#pragma unroll 8
  for (int o = 0; o < CC; ++o)
    acc += w1[o * CC + c] * w2[o * CC + cp];
  M[c * CC + cp] = acc;
  if (c == 0) {
    float ga = 0.f;
    for (int o = 0; o < CC; ++o)
      ga += b1[o] * w2[o * CC + cp];
    g[cp] = ga;
  }
}

// K-cvt: x2 tile -> kimg (swizzled [j][c], RNE fp16) + vimg (natural [c][32j],
// RNE fp16) + r2[b,j] = sum_c g[c]*x2[b,c,j].
// K image row j (512B): 16B slot st holds halves c=8s..8s+7 with s = st^(j&7).
__global__ void k_cvt(const float* __restrict__ x2, const float* __restrict__ g,
                      ush* __restrict__ kimg, ush* __restrict__ vimg,
                      float* __restrict__ r2) {
  __shared__ float Xs[256 * 37];
  __shared__ float Ps[32 * 9];
  const int tid = threadIdx.x;
  const int b   = blockIdx.x >> 7;
  const int jt  = blockIdx.x & 127;
  const int j0  = jt << 5;
  const float* x2b = x2 + ((size_t)b << 20);
  {
    const int jf = tid & 7, c0 = tid >> 3;
#pragma unroll
    for (int m = 0; m < 8; ++m) {
      int c = c0 + (m << 5);
      float4 v = *(const float4*)(x2b + ((size_t)c << 12) + j0 + (jf << 2));
      *(float4*)(Xs + c * 37 + (jf << 2)) = v;
    }
  }
  __syncthreads();
  const size_t tile = ((size_t)blockIdx.x) << 13;   // halves
  {
    ush* kp = kimg + tile;
#pragma unroll
    for (int m = 0; m < 4; ++m) {
      int idx = tid + (m << 8);
      int j = idx >> 5, st = idx & 31;
      int s = st ^ (j & 7);
      u32 hw[4];
#pragma unroll
      for (int k = 0; k < 4; ++k) {
        float a  = Xs[(8 * s + 2 * k) * 37 + j];
        float c2 = Xs[(8 * s + 2 * k + 1) * 37 + j];
        hw[k] = (u32)f2h(a) | ((u32)f2h(c2) << 16);
      }
      u32x4 v; v.x = hw[0]; v.y = hw[1]; v.z = hw[2]; v.w = hw[3];
      *(u32x4*)(kp + (idx << 3)) = v;
    }
  }
  {
    ush* vp = vimg + tile;
#pragma unroll
    for (int m = 0; m < 4; ++m) {
      int idx = tid + (m << 8);
      int c = idx >> 2, q = idx & 3;
      const float* xr = Xs + c * 37 + (q << 3);
      u32x4 v;
      v.x = (u32)f2h(xr[0]) | ((u32)f2h(xr[1]) << 16);
      v.y = (u32)f2h(xr[2]) | ((u32)f2h(xr[3]) << 16);
      v.z = (u32)f2h(xr[4]) | ((u32)f2h(xr[5]) << 16);
      v.w = (u32)f2h(xr[6]) | ((u32)f2h(xr[7]) << 16);
      *(u32x4*)(vp + (idx << 3)) = v;
    }
  }
  {
    const int j = tid & 31, s = tid >> 5;
    float acc = 0.f;
#pragma unroll 8
    for (int k = 0; k < 32; ++k)
      acc += g[(s << 5) + k] * Xs[((s << 5) + k) * 37 + j];
    Ps[j * 9 + s] = acc;
  }
  __syncthreads();
  if (tid < 32) {
    float a = 0.f;
#pragma unroll
    for (int s = 0; s < 8; ++s) a += Ps[tid * 9 + s];
    r2[(b << 12) + j0 + tid] = a;
  }
}

// K3: Q-prep + flash attention; K via DMA dbuf LDS, V direct global->reg,
// single-pass fp16 S (RNE operands).
__launch_bounds__(256, 3)
__global__ void k_attn(const float* __restrict__ x1, const ush* __restrict__ kimg,
                       const ush* __restrict__ vimg, const float* __restrict__ M,
                       const float* __restrict__ r2, float* __restrict__ out) {
  extern __shared__ ush lds[];
  const int tid  = threadIdx.x;
  const int lane = tid & 63;
  const int w    = tid >> 6;
  const int p    = w >> 1;
  const int h    = w & 1;
  const int g    = lane >> 4;
  const int lq   = lane & 15;

  int bid = (int)blockIdx.x;
  bid = (bid & 7) * 64 + (bid >> 3);        // bijective XCD swizzle (512 = 8*64)
  const int b  = bid >> 7;
  const int i0 = (bid & 127) << 5;

  const float* x1b = x1 + ((size_t)b << 20);

  // ---- Q-prep (VALU f32, two 16-i passes); x1f @0, Qhi @ byte 18432 ----
  float* x1f = (float*)lds;                 // [256][18] f32
  ush* Qhi = lds + 9216;                    // [32][256] halves
  for (int ih = 0; ih < 2; ++ih) {
    {
      const int jf = tid & 3, c0 = tid >> 2;
#pragma unroll
      for (int m = 0; m < 4; ++m) {
        int c = c0 + (m << 6);
        float4 v = *(const float4*)(x1b + ((size_t)c << 12) + i0 + (ih << 4) + (jf << 2));
        *(float4*)(x1f + c * 18 + (jf << 2)) = v;
      }
    }
    __syncthreads();
    {
      const int tc = tid & 63, tq = tid >> 6;
      float acc[4][4];
#pragma unroll
      for (int q = 0; q < 4; ++q)
#pragma unroll
        for (int e = 0; e < 4; ++e) acc[q][e] = 0.f;
#pragma unroll 4
      for (int c = 0; c < CC; ++c) {
        float4 mv = *(const float4*)(M + c * CC + (tc << 2));
        float4 xs = *(const float4*)(x1f + c * 18 + (tq << 2));
        float xv[4] = {xs.x, xs.y, xs.z, xs.w};
#pragma unroll
        for (int e = 0; e < 4; ++e) {
          acc[0][e] += mv.x * xv[e];
          acc[1][e] += mv.y * xv[e];
          acc[2][e] += mv.z * xv[e];
          acc[3][e] += mv.w * xv[e];
        }
      }
#pragma unroll
      for (int e = 0; e < 4; ++e) {
        int i = (ih << 4) + (tq << 2) + e;
        u32 h0 = (u32)f2h(acc[0][e]) | ((u32)f2h(acc[1][e]) << 16);
        u32 h1 = (u32)f2h(acc[2][e]) | ((u32)f2h(acc[3][e]) << 16);
        u32x2 hw; hw.x = h0; hw.y = h1;
        *(u32x2*)(Qhi + (i << 8) + (tc << 2)) = hw;
      }
    }
    __syncthreads();
  }

  // ---- preload Q fragments ----
  Frag8 QBh[8];
  {
    const int qoff = ((p << 4) + lq) << 8;
#pragma unroll
    for (int cs = 0; cs < 8; ++cs)
      QBh[cs].u4 = *(const u32x4*)(Qhi + qoff + (cs << 5) + (g << 3));
  }
  __syncthreads();

  // ---- main flash loop ----
  f32x4 vacc[16];
#pragma unroll
  for (int ct = 0; ct < 16; ++ct) vacc[ct] = (f32x4){0.f, 0.f, 0.f, 0.f};
  float m_run = -3.0e38f, l_run = 0.f;

  const int jrow = (h << 4) + lq;
  const int sx   = lq & 7;
  const int koff = jrow << 8;               // halves
  const float* r2p = r2 + (b << 12) + (h << 4) + (g << 2);
  const size_t bt = (size_t)(b << 7);
  const ush* vbase = vimg + (bt << 13) + (lq << 5) + (h << 4) + (g << 2);

  // prologue: stage K tile 0 into buf0
  {
    const ush* gk = kimg + (bt << 13);
#pragma unroll
    for (int m = 0; m < 4; ++m) {
      int idx = tid + (m << 8);
      gload16(gk + (idx << 3), lds + (idx << 3));
    }
  }
  __syncthreads();

  for (int t = 0; t < 128; ++t) {
    const int cur = (t & 1) << 13;
    // V(t) -> regs (b64 per lane) + r2 prefetch (issued before K-DMA so the
    // PV waitcnt leaves the 8 K-DMA loads in flight)
    Frag4 Vf[16];
    const ush* vt_ = vbase + ((size_t)t << 13);
#pragma unroll
    for (int ct = 0; ct < 16; ++ct)
      Vf[ct].u2 = *(const u32x2*)(vt_ + (ct << 9));
    float4 r2v = *(const float4*)(r2p + (t << 5));
    // K DMA for t+1
    if (t + 1 < 128) {
      const int nxt = ((t + 1) & 1) << 13;
      const ush* gk = kimg + ((bt + t + 1) << 13);
#pragma unroll
      for (int m = 0; m < 4; ++m) {
        int idx = tid + (m << 8);
        gload16(gk + (idx << 3), lds + nxt + (idx << 3));
      }
    }
    const ush* kb = lds + cur;

    // S^T = K·Q (single pass, RNE operands)
    f32x4 a1 = {0.f, 0.f, 0.f, 0.f};
#pragma unroll
    for (int cs = 0; cs < 8; ++cs) {
      int st = ((cs << 2) + g) ^ sx;
      Frag8 Ah; Ah.u4 = *(const u32x4*)(kb + koff + (st << 3));
      a1 = MFMA32(Ah.f, QBh[cs].f, a1);
    }

    // online softmax (rows i = 16p+lq; j = 32t + 16h + 4g + r)
    float s0 = a1[0] + r2v.x, s1 = a1[1] + r2v.y;
    float s2 = a1[2] + r2v.z, s3 = a1[3] + r2v.w;
    float mx = fmaxf(fmaxf(s0, s1), fmaxf(s2, s3));
    mx = fmaxf(mx, __shfl_xor(mx, 16));
    mx = fmaxf(mx, __shfl_xor(mx, 32));
    float mn = fmaxf(m_run, mx);
    int stb = (mn == m_run) ? 1 : 0;
    float scl = __expf(m_run - mn);
    float p0 = __expf(s0 - mn), p1 = __expf(s1 - mn);
    float p2 = __expf(s2 - mn), p3 = __expf(s3 - mn);
    float rs = p0 + p1 + p2 + p3;
    rs += __shfl_xor(rs, 16);
    rs += __shfl_xor(rs, 32);
    l_run = l_run * scl + rs;
    m_run = mn;

    Frag4 Pf;
    Pf.u2.x = pkrtz(p0, p1);
    Pf.u2.y = pkrtz(p2, p3);

    if (!__all(stb)) {
#pragma unroll
      for (int ct = 0; ct < 16; ++ct) {
        vacc[ct][0] *= scl; vacc[ct][1] *= scl;
        vacc[ct][2] *= scl; vacc[ct][3] *= scl;
      }
    }
#pragma unroll
    for (int ct = 0; ct < 16; ++ct)
      vacc[ct] = MFMA16(Vf[ct].f, Pf.f, vacc[ct]);
    __syncthreads();
  }

  // ---- merge j-halves, normalize, store ----
  float* Cmb = (float*)lds;                          // [2][256][17] f32
  float* Msm = (float*)(lds + 17408);                // byte 34816
  float* Lsm = Msm + 64;
  if (g == 0) {
    Msm[p * 32 + h * 16 + lq] = m_run;
    Lsm[p * 32 + h * 16 + lq] = l_run;
  }
  __syncthreads();
  float mo  = Msm[p * 32 + (1 - h) * 16 + lq];
  float lo2 = Lsm[p * 32 + (1 - h) * 16 + lq];
  float mt    = fmaxf(m_run, mo);
  float aSelf = __expf(m_run - mt);
  float l_tot = l_run * aSelf + lo2 * __expf(mo - mt);

  if (h == 0) {
    float* cb_ = Cmb + p * (CC * RSC);
#pragma unroll
    for (int ct = 0; ct < 16; ++ct)
#pragma unroll
      for (int r = 0; r < 4; ++r)
        cb_[((ct << 4) + (g << 2) + r) * RSC + lq] = vacc[ct][r] * aSelf;
  }
  __syncthreads();
  if (h == 1) {
    const float* cb_ = Cmb + p * (CC * RSC);
    float inv = 1.f / l_tot;
    float* ob = out + ((size_t)b << 20) + i0 + (p << 4) + lq;
#pragma unroll
    for (int ct = 0; ct < 16; ++ct)
#pragma unroll
      for (int r = 0; r < 4; ++r) {
        int c = (ct << 4) + (g << 2) + r;
        ob[(size_t)c << 12] = (vacc[ct][r] * aSelf + cb_[c * RSC + lq]) * inv;
      }
  }
}

extern "C" void kernel_launch(void* const* d_in, const int* in_sizes, int n_in,
                              void* d_out, int out_size, void* d_ws, size_t ws_size,
                              hipStream_t stream) {
  const float* x1 = (const float*)d_in[0];
  const float* x2 = (const float*)d_in[1];
  const float* w1 = (const float*)d_in[2];
  const float* b1 = (const float*)d_in[3];
  const float* w2 = (const float*)d_in[4];
  // b2 (d_in[5]) contributes only row-constant energy terms -> cancels in softmax.

  float* M  = (float*)d_ws;            // 256KB
  float* g  = M + 65536;
  float* r2 = g + 256;                 // 64KB
  ush* kimg = (ush*)(r2 + 16384);      // 8MB, per-tile 16KB LDS byte-images
  ush* vimg = kimg + 4194304;          // 8MB, per-tile [c][32j] fp16
  float* outp = (float*)d_out;

  const int LDS_BYTES = 35328;
  (void)hipFuncSetAttribute((const void*)k_attn,
                            hipFuncAttributeMaxDynamicSharedMemorySize, LDS_BYTES);

  k_prep<<<CC, 256, 0, stream>>>(w1, w2, b1, M, g);
  k_cvt<<<BB * (NN / 32), 256, 0, stream>>>(x2, g, kimg, vimg, r2);
  k_attn<<<BB * (NN / 32), 256, LDS_BYTES, stream>>>(x1, kimg, vimg, M, r2, outp);
  (void)in_sizes; (void)n_in; (void)out_size; (void)ws_size;
}

// Round 8
// 290.208 us; speedup vs baseline: 1.2429x; 1.2429x over previous
//
#include <hip/hip_runtime.h>

typedef _Float16 f16;
typedef _Float16 f16x8 __attribute__((ext_vector_type(8)));
typedef _Float16 f16x4 __attribute__((ext_vector_type(4)));
typedef float    f32x4 __attribute__((ext_vector_type(4)));
typedef unsigned int u32;
typedef u32 u32x2 __attribute__((ext_vector_type(2)));
typedef u32 u32x4 __attribute__((ext_vector_type(4)));
typedef unsigned short ush;

#define CC 256
#define NN 4096
#define BB 4
#define RSC 17          // combine buffer stride (f32)

union Frag8 { u32x4 u4; f16x8 f; };
union Frag4 { u32x2 u2; f16x4 f; };

static __device__ __forceinline__ u32 pkrtz(float a, float b) {
  auto t = __builtin_amdgcn_cvt_pkrtz(a, b);
  return __builtin_bit_cast(u32, t);
}
static __device__ __forceinline__ ush f2h(float x) {   // RNE
  f16 h = (f16)x;
  return __builtin_bit_cast(ush, h);
}

static __device__ __forceinline__ void gload16(const ush* g, ush* l) {
  __builtin_amdgcn_global_load_lds(
      (const __attribute__((address_space(1))) u32*)g,
      (__attribute__((address_space(3))) u32*)l, 16, 0, 0);
}

#define MFMA32(A, B, C) __builtin_amdgcn_mfma_f32_16x16x32_f16((A), (B), (C), 0, 0, 0)
#define MFMA16(A, B, C) __builtin_amdgcn_mfma_f32_16x16x16f16((A), (B), (C), 0, 0, 0)

// K1: M[c][cp] = sum_o w1[o,c]*w2[o,cp] ; g[cp] = sum_o b1[o]*w2[o,cp]
__global__ void k_prep(const float* __restrict__ w1, const float* __restrict__ w2,
                       const float* __restrict__ b1, float* __restrict__ M,
                       float* __restrict__ g) {
  const int c  = blockIdx.x;
  const int cp = threadIdx.x;
  float acc = 0.f;
#pragma unroll 8
  for (int o = 0; o < CC; ++o)
    acc += w1[o * CC + c] * w2[o * CC + cp];
  M[c * CC + cp] = acc;
  if (c == 0) {
    float ga = 0.f;
    for (int o = 0; o < CC; ++o)
      ga += b1[o] * w2[o * CC + cp];
    g[cp] = ga;
  }
}

// K-cvt: x2 tile -> kimg (swizzled [j][c] LDS byte-image) + vimg (PV-fragment
// order: entry16B(m,h,g,lq) = {V[lq+32m][q0..q0+3], V[lq+32m+16][q0..q0+3]},
// q0 = 16h+4g) + r2[b,j] = sum_c g[c]*x2[b,c,j].   (all fp16 RNE)
// K image row j (512B): 16B slot st holds halves c=8s..8s+7 with s = st^(j&7).
__global__ void k_cvt(const float* __restrict__ x2, const float* __restrict__ g,
                      ush* __restrict__ kimg, ush* __restrict__ vimg,
                      float* __restrict__ r2) {
  __shared__ float Xs[256 * 37];
  __shared__ float Ps[32 * 9];
  const int tid = threadIdx.x;
  const int b   = blockIdx.x >> 7;
  const int jt  = blockIdx.x & 127;
  const int j0  = jt << 5;
  const float* x2b = x2 + ((size_t)b << 20);
  {
    const int jf = tid & 7, c0 = tid >> 3;
#pragma unroll
    for (int m = 0; m < 8; ++m) {
      int c = c0 + (m << 5);
      float4 v = *(const float4*)(x2b + ((size_t)c << 12) + j0 + (jf << 2));
      *(float4*)(Xs + c * 37 + (jf << 2)) = v;
    }
  }
  __syncthreads();
  const size_t tile = ((size_t)blockIdx.x) << 13;   // halves
  {
    ush* kp = kimg + tile;
#pragma unroll
    for (int m = 0; m < 4; ++m) {
      int idx = tid + (m << 8);
      int j = idx >> 5, st = idx & 31;
      int s = st ^ (j & 7);
      u32 hw[4];
#pragma unroll
      for (int k = 0; k < 4; ++k) {
        float a  = Xs[(8 * s + 2 * k) * 37 + j];
        float c2 = Xs[(8 * s + 2 * k + 1) * 37 + j];
        hw[k] = (u32)f2h(a) | ((u32)f2h(c2) << 16);
      }
      u32x4 v; v.x = hw[0]; v.y = hw[1]; v.z = hw[2]; v.w = hw[3];
      *(u32x4*)(kp + (idx << 3)) = v;
    }
  }
  {
    ush* vp = vimg + tile;
#pragma unroll
    for (int mm = 0; mm < 4; ++mm) {
      int e = tid + (mm << 8);
      int lqe = e & 15, ge = (e >> 4) & 3, he = (e >> 6) & 1, me = e >> 7;
      int c0 = lqe + (me << 5);
      int q0 = (he << 4) + (ge << 2);
      const float* r0 = Xs + c0 * 37 + q0;
      const float* r1 = Xs + (c0 + 16) * 37 + q0;
      u32x4 v;
      v.x = (u32)f2h(r0[0]) | ((u32)f2h(r0[1]) << 16);
      v.y = (u32)f2h(r0[2]) | ((u32)f2h(r0[3]) << 16);
      v.z = (u32)f2h(r1[0]) | ((u32)f2h(r1[1]) << 16);
      v.w = (u32)f2h(r1[2]) | ((u32)f2h(r1[3]) << 16);
      *(u32x4*)(vp + (e << 3)) = v;
    }
  }
  {
    const int j = tid & 31, s = tid >> 5;
    float acc = 0.f;
#pragma unroll 8
    for (int k = 0; k < 32; ++k)
      acc += g[(s << 5) + k] * Xs[((s << 5) + k) * 37 + j];
    Ps[j * 9 + s] = acc;
  }
  __syncthreads();
  if (tid < 32) {
    float a = 0.f;
#pragma unroll
    for (int s = 0; s < 8; ++s) a += Ps[tid * 9 + s];
    r2[(b << 12) + j0 + tid] = a;
  }
}

// K3: Q-prep + flash attention; K via DMA dbuf LDS, V coalesced global->reg,
// single-pass fp16 S (RNE) in two independent MFMA chains.
__launch_bounds__(256, 3)
__global__ void k_attn(const float* __restrict__ x1, const ush* __restrict__ kimg,
                       const ush* __restrict__ vimg, const float* __restrict__ M,
                       const float* __restrict__ r2, float* __restrict__ out) {
  extern __shared__ ush lds[];
  const int tid  = threadIdx.x;
  const int lane = tid & 63;
  const int w    = tid >> 6;
  const int p    = w >> 1;
  const int h    = w & 1;
  const int g    = lane >> 4;
  const int lq   = lane & 15;

  int bid = (int)blockIdx.x;
  bid = (bid & 7) * 64 + (bid >> 3);        // bijective XCD swizzle (512 = 8*64)
  const int b  = bid >> 7;
  const int i0 = (bid & 127) << 5;

  const float* x1b = x1 + ((size_t)b << 20);

  // ---- Q-prep (VALU f32, two 16-i passes); x1f @0, Qhi @ byte 18432 ----
  float* x1f = (float*)lds;                 // [256][18] f32
  ush* Qhi = lds + 9216;                    // [32][256] halves
  for (int ih = 0; ih < 2; ++ih) {
    {
      const int jf = tid & 3, c0 = tid >> 2;
#pragma unroll
      for (int m = 0; m < 4; ++m) {
        int c = c0 + (m << 6);
        float4 v = *(const float4*)(x1b + ((size_t)c << 12) + i0 + (ih << 4) + (jf << 2));
        *(float4*)(x1f + c * 18 + (jf << 2)) = v;
      }
    }
    __syncthreads();
    {
      const int tc = tid & 63, tq = tid >> 6;
      float acc[4][4];
#pragma unroll
      for (int q = 0; q < 4; ++q)
#pragma unroll
        for (int e = 0; e < 4; ++e) acc[q][e] = 0.f;
#pragma unroll 4
      for (int c = 0; c < CC; ++c) {
        float4 mv = *(const float4*)(M + c * CC + (tc << 2));
        float4 xs = *(const float4*)(x1f + c * 18 + (tq << 2));
        float xv[4] = {xs.x, xs.y, xs.z, xs.w};
#pragma unroll
        for (int e = 0; e < 4; ++e) {
          acc[0][e] += mv.x * xv[e];
          acc[1][e] += mv.y * xv[e];
          acc[2][e] += mv.z * xv[e];
          acc[3][e] += mv.w * xv[e];
        }
      }
#pragma unroll
      for (int e = 0; e < 4; ++e) {
        int i = (ih << 4) + (tq << 2) + e;
        u32 h0 = (u32)f2h(acc[0][e]) | ((u32)f2h(acc[1][e]) << 16);
        u32 h1 = (u32)f2h(acc[2][e]) | ((u32)f2h(acc[3][e]) << 16);
        u32x2 hw; hw.x = h0; hw.y = h1;
        *(u32x2*)(Qhi + (i << 8) + (tc << 2)) = hw;
      }
    }
    __syncthreads();
  }

  // ---- preload Q fragments ----
  Frag8 QBh[8];
  {
    const int qoff = ((p << 4) + lq) << 8;
#pragma unroll
    for (int cs = 0; cs < 8; ++cs)
      QBh[cs].u4 = *(const u32x4*)(Qhi + qoff + (cs << 5) + (g << 3));
  }
  __syncthreads();

  // ---- main flash loop ----
  f32x4 vacc[16];
#pragma unroll
  for (int ct = 0; ct < 16; ++ct) vacc[ct] = (f32x4){0.f, 0.f, 0.f, 0.f};
  float m_run = -3.0e38f, l_run = 0.f;

  const int jrow = (h << 4) + lq;
  const int sx   = lq & 7;
  const int koff = jrow << 8;               // halves
  const float* r2p = r2 + (b << 12) + (h << 4) + (g << 2);
  const size_t bt = (size_t)(b << 7);
  // vimg entry(m,h,g,lq): halves offset m*1024 + h*512 + g*128 + lq*8
  const ush* vbase = vimg + (bt << 13) + (h << 9) + (g << 7) + (lq << 3);

  // prologue: stage K tile 0 into buf0
  {
    const ush* gk = kimg + (bt << 13);
#pragma unroll
    for (int m = 0; m < 4; ++m) {
      int idx = tid + (m << 8);
      gload16(gk + (idx << 3), lds + (idx << 3));
    }
  }
  __syncthreads();

  for (int t = 0; t < 128; ++t) {
    const int cur = (t & 1) << 13;
    // r2 + V(t) -> regs: 8 coalesced b128 per lane (wave reads contiguous 1KB)
    float4 r2v = *(const float4*)(r2p + (t << 5));
    Frag8 Vd[8];
    const ush* vt_ = vbase + ((size_t)t << 13);
#pragma unroll
    for (int m = 0; m < 8; ++m)
      Vd[m].u4 = *(const u32x4*)(vt_ + (m << 10));
    // K DMA for t+1
    if (t + 1 < 128) {
      const int nxt = ((t + 1) & 1) << 13;
      const ush* gk = kimg + ((bt + t + 1) << 13);
#pragma unroll
      for (int m = 0; m < 4; ++m) {
        int idx = tid + (m << 8);
        gload16(gk + (idx << 3), lds + nxt + (idx << 3));
      }
    }
    const ush* kb = lds + cur;

    // S^T = K·Q (single pass, two independent chains)
    f32x4 a1 = {0.f, 0.f, 0.f, 0.f}, a2 = {0.f, 0.f, 0.f, 0.f};
#pragma unroll
    for (int cs = 0; cs < 8; cs += 2) {
      int st1 = ((cs << 2) + g) ^ sx;
      int st2 = (((cs + 1) << 2) + g) ^ sx;
      Frag8 A1; A1.u4 = *(const u32x4*)(kb + koff + (st1 << 3));
      Frag8 A2; A2.u4 = *(const u32x4*)(kb + koff + (st2 << 3));
      a1 = MFMA32(A1.f, QBh[cs].f, a1);
      a2 = MFMA32(A2.f, QBh[cs + 1].f, a2);
    }

    // online softmax (rows i = 16p+lq; j = 32t + 16h + 4g + r)
    float s0 = a1[0] + a2[0] + r2v.x, s1 = a1[1] + a2[1] + r2v.y;
    float s2 = a1[2] + a2[2] + r2v.z, s3 = a1[3] + a2[3] + r2v.w;
    float mx = fmaxf(fmaxf(s0, s1), fmaxf(s2, s3));
    mx = fmaxf(mx, __shfl_xor(mx, 16));
    mx = fmaxf(mx, __shfl_xor(mx, 32));
    float mn = fmaxf(m_run, mx);
    int stb = (mn == m_run) ? 1 : 0;
    float scl = __expf(m_run - mn);
    float p0 = __expf(s0 - mn), p1 = __expf(s1 - mn);
    float p2 = __expf(s2 - mn), p3 = __expf(s3 - mn);
    float rs = p0 + p1 + p2 + p3;
    rs += __shfl_xor(rs, 16);
    rs += __shfl_xor(rs, 32);
    l_run = l_run * scl + rs;
    m_run = mn;

    Frag4 Pf;
    Pf.u2.x = pkrtz(p0, p1);
    Pf.u2.y = pkrtz(p2, p3);

    if (!__all(stb)) {
#pragma unroll
      for (int ct = 0; ct < 16; ++ct) {
        vacc[ct][0] *= scl; vacc[ct][1] *= scl;
        vacc[ct][2] *= scl; vacc[ct][3] *= scl;
      }
    }
#pragma unroll
    for (int m = 0; m < 8; ++m) {
      Frag4 Va, Vb;
      Va.u2.x = Vd[m].u4.x; Va.u2.y = Vd[m].u4.y;     // ct = 2m
      Vb.u2.x = Vd[m].u4.z; Vb.u2.y = Vd[m].u4.w;     // ct = 2m+1
      vacc[2 * m]     = MFMA16(Va.f, Pf.f, vacc[2 * m]);
      vacc[2 * m + 1] = MFMA16(Vb.f, Pf.f, vacc[2 * m + 1]);
    }
    __syncthreads();
  }

  // ---- merge j-halves, normalize, store ----
  float* Cmb = (float*)lds;                          // [2][256][17] f32
  float* Msm = (float*)(lds + 17408);                // byte 34816
  float* Lsm = Msm + 64;
  if (g == 0) {
    Msm[p * 32 + h * 16 + lq] = m_run;
    Lsm[p * 32 + h * 16 + lq] = l_run;
  }
  __syncthreads();
  float mo  = Msm[p * 32 + (1 - h) * 16 + lq];
  float lo2 = Lsm[p * 32 + (1 - h) * 16 + lq];
  float mt    = fmaxf(m_run, mo);
  float aSelf = __expf(m_run - mt);
  float l_tot = l_run * aSelf + lo2 * __expf(mo - mt);

  if (h == 0) {
    float* cb_ = Cmb + p * (CC * RSC);
#pragma unroll
    for (int ct = 0; ct < 16; ++ct)
#pragma unroll
      for (int r = 0; r < 4; ++r)
        cb_[((ct << 4) + (g << 2) + r) * RSC + lq] = vacc[ct][r] * aSelf;
  }
  __syncthreads();
  if (h == 1) {
    const float* cb_ = Cmb + p * (CC * RSC);
    float inv = 1.f / l_tot;
    float* ob = out + ((size_t)b << 20) + i0 + (p << 4) + lq;
#pragma unroll
    for (int ct = 0; ct < 16; ++ct)
#pragma unroll
      for (int r = 0; r < 4; ++r) {
        int c = (ct << 4) + (g << 2) + r;
        ob[(size_t)c << 12] = (vacc[ct][r] * aSelf + cb_[c * RSC + lq]) * inv;
      }
  }
}

extern "C" void kernel_launch(void* const* d_in, const int* in_sizes, int n_in,
                              void* d_out, int out_size, void* d_ws, size_t ws_size,
                              hipStream_t stream) {
  const float* x1 = (const float*)d_in[0];
  const float* x2 = (const float*)d_in[1];
  const float* w1 = (const float*)d_in[2];
  const float* b1 = (const float*)d_in[3];
  const float* w2 = (const float*)d_in[4];
  // b2 (d_in[5]) contributes only row-constant energy terms -> cancels in softmax.

  float* M  = (float*)d_ws;            // 256KB
  float* g  = M + 65536;
  float* r2 = g + 256;                 // 64KB
  ush* kimg = (ush*)(r2 + 16384);      // 8MB, per-tile 16KB LDS byte-images
  ush* vimg = kimg + 4194304;          // 8MB, per-tile PV-fragment-ordered fp16
  float* outp = (float*)d_out;

  const int LDS_BYTES = 35328;
  (void)hipFuncSetAttribute((const void*)k_attn,
                            hipFuncAttributeMaxDynamicSharedMemorySize, LDS_BYTES);

  k_prep<<<CC, 256, 0, stream>>>(w1, w2, b1, M, g);
  k_cvt<<<BB * (NN / 32), 256, 0, stream>>>(x2, g, kimg, vimg, r2);
  k_attn<<<BB * (NN / 32), 256, LDS_BYTES, stream>>>(x1, kimg, vimg, M, r2, outp);
  (void)in_sizes; (void)n_in; (void)out_size; (void)ws_size;
}

// Round 9
// 273.387 us; speedup vs baseline: 1.3193x; 1.0615x over previous
//
#include <hip/hip_runtime.h>

typedef _Float16 f16;
typedef _Float16 f16x8 __attribute__((ext_vector_type(8)));
typedef _Float16 f16x4 __attribute__((ext_vector_type(4)));
typedef float    f32x4 __attribute__((ext_vector_type(4)));
typedef unsigned int u32;
typedef u32 u32x2 __attribute__((ext_vector_type(2)));
typedef u32 u32x4 __attribute__((ext_vector_type(4)));
typedef unsigned short ush;

#define CC 256
#define NN 4096
#define BB 4
#define RSC 17          // combine buffer stride (f32)

union Frag8 { u32x4 u4; f16x8 f; };
union Frag4 { u32x2 u2; f16x4 f; };

static __device__ __forceinline__ u32 pkrtz(float a, float b) {
  auto t = __builtin_amdgcn_cvt_pkrtz(a, b);
  return __builtin_bit_cast(u32, t);
}
static __device__ __forceinline__ ush f2h(float x) {   // RNE
  f16 h = (f16)x;
  return __builtin_bit_cast(ush, h);
}

static __device__ __forceinline__ void gload16(const ush* g, ush* l) {
  __builtin_amdgcn_global_load_lds(
      (const __attribute__((address_space(1))) u32*)g,
      (__attribute__((address_space(3))) u32*)l, 16, 0, 0);
}

#define MFMA32(A, B, C) __builtin_amdgcn_mfma_f32_16x16x32_f16((A), (B), (C), 0, 0, 0)
#define MFMA16(A, B, C) __builtin_amdgcn_mfma_f32_16x16x16f16((A), (B), (C), 0, 0, 0)

// K1: M[c][cp] = sum_o w1[o,c]*w2[o,cp] ; g[cp] = sum_o b1[o]*w2[o,cp]
__global__ void k_prep(const float* __restrict__ w1, const float* __restrict__ w2,
                       const float* __restrict__ b1, float* __restrict__ M,
                       float* __restrict__ g) {
  const int c  = blockIdx.x;
  const int cp = threadIdx.x;
  float acc = 0.f;
#pragma unroll 8
  for (int o = 0; o < CC; ++o)
    acc += w1[o * CC + c] * w2[o * CC + cp];
  M[c * CC + cp] = acc;
  if (c == 0) {
    float ga = 0.f;
    for (int o = 0; o < CC; ++o)
      ga += b1[o] * w2[o * CC + cp];
    g[cp] = ga;
  }
}

// K-cvt: x2 tile -> kimg (swizzled [j][c] LDS byte-image) + vimg (PV-fragment
// order: entry16B(m,h,g,lq) = {V[lq+32m][q0..q0+3], V[lq+32m+16][q0..q0+3]},
// q0 = 16h+4g) + r2[b,j] = sum_c g[c]*x2[b,c,j].   (all fp16 RNE)
// K image row j (512B): 16B slot st holds halves c=8s..8s+7 with s = st^(j&7).
__global__ void k_cvt(const float* __restrict__ x2, const float* __restrict__ g,
                      ush* __restrict__ kimg, ush* __restrict__ vimg,
                      float* __restrict__ r2) {
  __shared__ float Xs[256 * 37];
  __shared__ float Ps[32 * 9];
  const int tid = threadIdx.x;
  const int b   = blockIdx.x >> 7;
  const int jt  = blockIdx.x & 127;
  const int j0  = jt << 5;
  const float* x2b = x2 + ((size_t)b << 20);
  {
    const int jf = tid & 7, c0 = tid >> 3;
#pragma unroll
    for (int m = 0; m < 8; ++m) {
      int c = c0 + (m << 5);
      float4 v = *(const float4*)(x2b + ((size_t)c << 12) + j0 + (jf << 2));
      *(float4*)(Xs + c * 37 + (jf << 2)) = v;
    }
  }
  __syncthreads();
  const size_t tile = ((size_t)blockIdx.x) << 13;   // halves
  {
    ush* kp = kimg + tile;
#pragma unroll
    for (int m = 0; m < 4; ++m) {
      int idx = tid + (m << 8);
      int j = idx >> 5, st = idx & 31;
      int s = st ^ (j & 7);
      u32 hw[4];
#pragma unroll
      for (int k = 0; k < 4; ++k) {
        float a  = Xs[(8 * s + 2 * k) * 37 + j];
        float c2 = Xs[(8 * s + 2 * k + 1) * 37 + j];
        hw[k] = (u32)f2h(a) | ((u32)f2h(c2) << 16);
      }
      u32x4 v; v.x = hw[0]; v.y = hw[1]; v.z = hw[2]; v.w = hw[3];
      *(u32x4*)(kp + (idx << 3)) = v;
    }
  }
  {
    ush* vp = vimg + tile;
#pragma unroll
    for (int mm = 0; mm < 4; ++mm) {
      int e = tid + (mm << 8);
      int lqe = e & 15, ge = (e >> 4) & 3, he = (e >> 6) & 1, me = e >> 7;
      int c0 = lqe + (me << 5);
      int q0 = (he << 4) + (ge << 2);
      const float* r0 = Xs + c0 * 37 + q0;
      const float* r1 = Xs + (c0 + 16) * 37 + q0;
      u32x4 v;
      v.x = (u32)f2h(r0[0]) | ((u32)f2h(r0[1]) << 16);
      v.y = (u32)f2h(r0[2]) | ((u32)f2h(r0[3]) << 16);
      v.z = (u32)f2h(r1[0]) | ((u32)f2h(r1[1]) << 16);
      v.w = (u32)f2h(r1[2]) | ((u32)f2h(r1[3]) << 16);
      *(u32x4*)(vp + (e << 3)) = v;
    }
  }
  {
    const int j = tid & 31, s = tid >> 5;
    float acc = 0.f;
#pragma unroll 8
    for (int k = 0; k < 32; ++k)
      acc += g[(s << 5) + k] * Xs[((s << 5) + k) * 37 + j];
    Ps[j * 9 + s] = acc;
  }
  __syncthreads();
  if (tid < 32) {
    float a = 0.f;
#pragma unroll
    for (int s = 0; s < 8; ++s) a += Ps[tid * 9 + s];
    r2[(b << 12) + j0 + tid] = a;
  }
}

// K3: QT=16, 128-thread blocks (2 waves, j-split), grid 1024.
// K via DMA dbuf LDS with counted-vmcnt pipeline (never vmcnt(0) in loop),
// V coalesced global->reg prefetched 1 tile ahead, single-pass fp16 S.
__launch_bounds__(128, 2)
__global__ void k_attn(const float* __restrict__ x1, const ush* __restrict__ kimg,
                       const ush* __restrict__ vimg, const float* __restrict__ M,
                       const float* __restrict__ r2, float* __restrict__ out) {
  extern __shared__ ush lds[];
  const int tid  = threadIdx.x;
  const int lane = tid & 63;
  const int h    = tid >> 6;       // wave = j-group
  const int g    = lane >> 4;
  const int lq   = lane & 15;

  int bid = (int)blockIdx.x;
  bid = (bid & 7) * 128 + (bid >> 3);       // bijective XCD swizzle (1024 = 8*128)
  const int b  = bid >> 8;
  const int i0 = (bid & 255) << 4;

  const float* x1b = x1 + ((size_t)b << 20);

  // ---- Q-prep (VALU f32): x1f @0 (18KB), Qhi @ byte 18432 (8KB) ----
  float* x1f = (float*)lds;                 // [256][18] f32
  ush* Qhi = lds + 9216;                    // [16][256] halves
  {
    const int jf = tid & 3, c0 = tid >> 2;
#pragma unroll
    for (int m = 0; m < 8; ++m) {
      int c = c0 + (m << 5);
      float4 v = *(const float4*)(x1b + ((size_t)c << 12) + i0 + (jf << 2));
      *(float4*)(x1f + c * 18 + (jf << 2)) = v;
    }
  }
  __syncthreads();
  {
    const int tc = tid & 63, iq = tid >> 6;
    float acc[4][8];
#pragma unroll
    for (int q = 0; q < 4; ++q)
#pragma unroll
      for (int e = 0; e < 8; ++e) acc[q][e] = 0.f;
#pragma unroll 4
    for (int c = 0; c < CC; ++c) {
      float4 mv = *(const float4*)(M + c * CC + (tc << 2));
      float4 xa = *(const float4*)(x1f + c * 18 + (iq << 3));
      float4 xb = *(const float4*)(x1f + c * 18 + (iq << 3) + 4);
      float xs[8] = {xa.x, xa.y, xa.z, xa.w, xb.x, xb.y, xb.z, xb.w};
#pragma unroll
      for (int e = 0; e < 8; ++e) {
        acc[0][e] += mv.x * xs[e];
        acc[1][e] += mv.y * xs[e];
        acc[2][e] += mv.z * xs[e];
        acc[3][e] += mv.w * xs[e];
      }
    }
    __syncthreads();
#pragma unroll
    for (int e = 0; e < 8; ++e) {
      int i = (iq << 3) + e;
      u32 h0 = (u32)f2h(acc[0][e]) | ((u32)f2h(acc[1][e]) << 16);
      u32 h1 = (u32)f2h(acc[2][e]) | ((u32)f2h(acc[3][e]) << 16);
      u32x2 hw; hw.x = h0; hw.y = h1;
      *(u32x2*)(Qhi + (i << 8) + (tc << 2)) = hw;
    }
  }
  __syncthreads();

  // ---- preload Q fragments ----
  Frag8 QBh[8];
  {
    const int qoff = lq << 8;
#pragma unroll
    for (int cs = 0; cs < 8; ++cs)
      QBh[cs].u4 = *(const u32x4*)(Qhi + qoff + (cs << 5) + (g << 3));
  }
  __syncthreads();

  // ---- main flash loop ----
  f32x4 vacc[16];
#pragma unroll
  for (int ct = 0; ct < 16; ++ct) vacc[ct] = (f32x4){0.f, 0.f, 0.f, 0.f};
  float m_run = -3.0e38f, l_run = 0.f;

  const int jrow = (h << 4) + lq;
  const int sx   = lq & 7;
  const int koff = jrow << 8;               // halves
  const float* r2p = r2 + (b << 12) + (h << 4) + (g << 2);
  const size_t bt = (size_t)(b << 7);
  const ush* vbase = vimg + (bt << 13) + (h << 9) + (g << 7) + (lq << 3);

  // prologue: K(0) DMA into buf0, V(0) loads; wait K only.
  Frag8 Vd[8];
  {
    const ush* gk = kimg + (bt << 13);
#pragma unroll
    for (int m = 0; m < 8; ++m) {
      int idx = tid + (m << 7);
      gload16(gk + (idx << 3), lds + (idx << 3));
    }
    const ush* vt_ = vbase;
#pragma unroll
    for (int m = 0; m < 8; ++m)
      Vd[m].u4 = *(const u32x4*)(vt_ + (m << 10));
  }
  asm volatile("s_waitcnt vmcnt(8)" ::: "memory");   // K(0) done, V(0) flying
  __builtin_amdgcn_sched_barrier(0);
  __builtin_amdgcn_s_barrier();

  int cur = 0;
  for (int t = 0; t < 128; ++t) {
    // issue K-DMA(t+1) into the other buffer (freed by last iter's barrier)
    if (t + 1 < 128) {
      const int nxt = cur ^ 8192;           // halves offset of other 16KB buf
      const ush* gk = kimg + ((bt + t + 1) << 13);
#pragma unroll
      for (int m = 0; m < 8; ++m) {
        int idx = tid + (m << 7);
        gload16(gk + (idx << 3), lds + nxt + (idx << 3));
      }
    }
    const ush* kb = lds + cur;

    // S^T = K·Q (single pass, two independent chains)
    f32x4 a1 = {0.f, 0.f, 0.f, 0.f}, a2 = {0.f, 0.f, 0.f, 0.f};
#pragma unroll
    for (int cs = 0; cs < 8; cs += 2) {
      int st1 = ((cs << 2) + g) ^ sx;
      int st2 = (((cs + 1) << 2) + g) ^ sx;
      Frag8 A1; A1.u4 = *(const u32x4*)(kb + koff + (st1 << 3));
      Frag8 A2; A2.u4 = *(const u32x4*)(kb + koff + (st2 << 3));
      a1 = MFMA32(A1.f, QBh[cs].f, a1);
      a2 = MFMA32(A2.f, QBh[cs + 1].f, a2);
    }

    // online softmax (rows i = lq; j = 32t + 16h + 4g + r)
    float4 r2v = *(const float4*)(r2p + (t << 5));
    float s0 = a1[0] + a2[0] + r2v.x, s1 = a1[1] + a2[1] + r2v.y;
    float s2 = a1[2] + a2[2] + r2v.z, s3 = a1[3] + a2[3] + r2v.w;
    float mx = fmaxf(fmaxf(s0, s1), fmaxf(s2, s3));
    mx = fmaxf(mx, __shfl_xor(mx, 16));
    mx = fmaxf(mx, __shfl_xor(mx, 32));
    float mn = fmaxf(m_run, mx);
    int stb = (mn == m_run) ? 1 : 0;
    float scl = __expf(m_run - mn);
    float p0 = __expf(s0 - mn), p1 = __expf(s1 - mn);
    float p2 = __expf(s2 - mn), p3 = __expf(s3 - mn);
    float rs = p0 + p1 + p2 + p3;
    rs += __shfl_xor(rs, 16);
    rs += __shfl_xor(rs, 32);
    l_run = l_run * scl + rs;
    m_run = mn;

    Frag4 Pf;
    Pf.u2.x = pkrtz(p0, p1);
    Pf.u2.y = pkrtz(p2, p3);

    // wait V(t) (K-DMA(t+1) stays in flight)
    if (t + 1 < 128) {
      asm volatile("s_waitcnt vmcnt(8)" ::: "memory");
    } else {
      asm volatile("s_waitcnt vmcnt(0)" ::: "memory");
    }
    __builtin_amdgcn_sched_barrier(0);

    if (!__all(stb)) {
#pragma unroll
      for (int ct = 0; ct < 16; ++ct) {
        vacc[ct][0] *= scl; vacc[ct][1] *= scl;
        vacc[ct][2] *= scl; vacc[ct][3] *= scl;
      }
    }
#pragma unroll
    for (int m = 0; m < 8; ++m) {
      Frag4 Va, Vb;
      Va.u2.x = Vd[m].u4.x; Va.u2.y = Vd[m].u4.y;     // ct = 2m
      Vb.u2.x = Vd[m].u4.z; Vb.u2.y = Vd[m].u4.w;     // ct = 2m+1
      vacc[2 * m]     = MFMA16(Va.f, Pf.f, vacc[2 * m]);
      vacc[2 * m + 1] = MFMA16(Vb.f, Pf.f, vacc[2 * m + 1]);
    }

    if (t + 1 < 128) {
      // prefetch V(t+1) into Vd (regs free after PV issue)
      const ush* vt_ = vbase + ((size_t)(t + 1) << 13);
#pragma unroll
      for (int m = 0; m < 8; ++m)
        Vd[m].u4 = *(const u32x4*)(vt_ + (m << 10));
      // drain K-DMA(t+1) only (V(t+1) stays in flight), then cross-wave barrier
      asm volatile("s_waitcnt vmcnt(8)" ::: "memory");
      __builtin_amdgcn_sched_barrier(0);
      __builtin_amdgcn_s_barrier();
    }
    cur ^= 8192;
  }

  // ---- merge j-halves, normalize, store ----
  __syncthreads();
  float* Cmb = (float*)lds;                 // [256][17] f32 = 17408B
  float* Msm = (float*)(lds + 8704);        // byte 17408
  float* Lsm = Msm + 32;
  if (g == 0) {
    Msm[h * 16 + lq] = m_run;
    Lsm[h * 16 + lq] = l_run;
  }
  __syncthreads();
  float mo  = Msm[(1 - h) * 16 + lq];
  float lo2 = Lsm[(1 - h) * 16 + lq];
  float mt    = fmaxf(m_run, mo);
  float aSelf = __expf(m_run - mt);
  float l_tot = l_run * aSelf + lo2 * __expf(mo - mt);

  if (h == 0) {
#pragma unroll
    for (int ct = 0; ct < 16; ++ct)
#pragma unroll
      for (int r = 0; r < 4; ++r)
        Cmb[((ct << 4) + (g << 2) + r) * RSC + lq] = vacc[ct][r] * aSelf;
  }
  __syncthreads();
  if (h == 1) {
    float inv = 1.f / l_tot;
    float* ob = out + ((size_t)b << 20) + i0 + lq;
#pragma unroll
    for (int ct = 0; ct < 16; ++ct)
#pragma unroll
      for (int r = 0; r < 4; ++r) {
        int c = (ct << 4) + (g << 2) + r;
        ob[(size_t)c << 12] = (vacc[ct][r] * aSelf + Cmb[c * RSC + lq]) * inv;
      }
  }
}

extern "C" void kernel_launch(void* const* d_in, const int* in_sizes, int n_in,
                              void* d_out, int out_size, void* d_ws, size_t ws_size,
                              hipStream_t stream) {
  const float* x1 = (const float*)d_in[0];
  const float* x2 = (const float*)d_in[1];
  const float* w1 = (const float*)d_in[2];
  const float* b1 = (const float*)d_in[3];
  const float* w2 = (const float*)d_in[4];
  // b2 (d_in[5]) contributes only row-constant energy terms -> cancels in softmax.

  float* M  = (float*)d_ws;            // 256KB
  float* g  = M + 65536;
  float* r2 = g + 256;                 // 64KB
  ush* kimg = (ush*)(r2 + 16384);      // 8MB, per-tile 16KB LDS byte-images
  ush* vimg = kimg + 4194304;          // 8MB, per-tile PV-fragment-ordered fp16
  float* outp = (float*)d_out;

  const int LDS_BYTES = 32768;
  (void)hipFuncSetAttribute((const void*)k_attn,
                            hipFuncAttributeMaxDynamicSharedMemorySize, LDS_BYTES);

  k_prep<<<CC, 256, 0, stream>>>(w1, w2, b1, M, g);
  k_cvt<<<BB * (NN / 32), 256, 0, stream>>>(x2, g, kimg, vimg, r2);
  k_attn<<<BB * (NN / 16), 128, LDS_BYTES, stream>>>(x1, kimg, vimg, M, r2, outp);
  (void)in_sizes; (void)n_in; (void)out_size; (void)ws_size;
}

// Round 10
// 271.515 us; speedup vs baseline: 1.3284x; 1.0069x over previous
//
#include <hip/hip_runtime.h>

typedef _Float16 f16;
typedef _Float16 f16x8 __attribute__((ext_vector_type(8)));
typedef _Float16 f16x4 __attribute__((ext_vector_type(4)));
typedef float    f32x4 __attribute__((ext_vector_type(4)));
typedef unsigned int u32;
typedef u32 u32x2 __attribute__((ext_vector_type(2)));
typedef u32 u32x4 __attribute__((ext_vector_type(4)));
typedef unsigned short ush;

#define CC 256
#define NN 4096
#define BB 4
#define RSC 17          // combine buffer stride (f32)

union Frag8 { u32x4 u4; f16x8 f; };
union Frag4 { u32x2 u2; f16x4 f; };

static __device__ __forceinline__ u32 pkrtz(float a, float b) {
  auto t = __builtin_amdgcn_cvt_pkrtz(a, b);
  return __builtin_bit_cast(u32, t);
}
static __device__ __forceinline__ ush f2h(float x) {   // RNE
  f16 h = (f16)x;
  return __builtin_bit_cast(ush, h);
}

static __device__ __forceinline__ void gload16(const ush* g, ush* l) {
  __builtin_amdgcn_global_load_lds(
      (const __attribute__((address_space(1))) u32*)g,
      (__attribute__((address_space(3))) u32*)l, 16, 0, 0);
}

#define MFMA32(A, B, C) __builtin_amdgcn_mfma_f32_16x16x32_f16((A), (B), (C), 0, 0, 0)
#define MFMA16(A, B, C) __builtin_amdgcn_mfma_f32_16x16x16f16((A), (B), (C), 0, 0, 0)

// K1: M[c][cp] = sum_o w1[o,c]*w2[o,cp] ; g[cp] = sum_o b1[o]*w2[o,cp]
__global__ void k_prep(const float* __restrict__ w1, const float* __restrict__ w2,
                       const float* __restrict__ b1, float* __restrict__ M,
                       float* __restrict__ g) {
  const int c  = blockIdx.x;
  const int cp = threadIdx.x;
  float acc = 0.f;
#pragma unroll 8
  for (int o = 0; o < CC; ++o)
    acc += w1[o * CC + c] * w2[o * CC + cp];
  M[c * CC + cp] = acc;
  if (c == 0) {
    float ga = 0.f;
    for (int o = 0; o < CC; ++o)
      ga += b1[o] * w2[o * CC + cp];
    g[cp] = ga;
  }
}

// K-cvt: x2 tile -> kimg (swizzled [j][c] LDS byte-image) + vimg (PV-fragment
// order) + r2[b,j] = sum_c g[c]*x2[b,c,j].   (all fp16 RNE)
// K image row j (512B): 16B slot st holds halves c=8s..8s+7 with s = st^(j&7).
__global__ void k_cvt(const float* __restrict__ x2, const float* __restrict__ g,
                      ush* __restrict__ kimg, ush* __restrict__ vimg,
                      float* __restrict__ r2) {
  __shared__ float Xs[256 * 37];
  __shared__ float Ps[32 * 9];
  const int tid = threadIdx.x;
  const int b   = blockIdx.x >> 7;
  const int jt  = blockIdx.x & 127;
  const int j0  = jt << 5;
  const float* x2b = x2 + ((size_t)b << 20);
  {
    const int jf = tid & 7, c0 = tid >> 3;
#pragma unroll
    for (int m = 0; m < 8; ++m) {
      int c = c0 + (m << 5);
      float4 v = *(const float4*)(x2b + ((size_t)c << 12) + j0 + (jf << 2));
      *(float4*)(Xs + c * 37 + (jf << 2)) = v;
    }
  }
  __syncthreads();
  const size_t tile = ((size_t)blockIdx.x) << 13;   // halves
  {
    ush* kp = kimg + tile;
#pragma unroll
    for (int m = 0; m < 4; ++m) {
      int idx = tid + (m << 8);
      int j = idx >> 5, st = idx & 31;
      int s = st ^ (j & 7);
      u32 hw[4];
#pragma unroll
      for (int k = 0; k < 4; ++k) {
        float a  = Xs[(8 * s + 2 * k) * 37 + j];
        float c2 = Xs[(8 * s + 2 * k + 1) * 37 + j];
        hw[k] = (u32)f2h(a) | ((u32)f2h(c2) << 16);
      }
      u32x4 v; v.x = hw[0]; v.y = hw[1]; v.z = hw[2]; v.w = hw[3];
      *(u32x4*)(kp + (idx << 3)) = v;
    }
  }
  {
    ush* vp = vimg + tile;
#pragma unroll
    for (int mm = 0; mm < 4; ++mm) {
      int e = tid + (mm << 8);
      int lqe = e & 15, ge = (e >> 4) & 3, he = (e >> 6) & 1, me = e >> 7;
      int c0 = lqe + (me << 5);
      int q0 = (he << 4) + (ge << 2);
      const float* r0 = Xs + c0 * 37 + q0;
      const float* r1 = Xs + (c0 + 16) * 37 + q0;
      u32x4 v;
      v.x = (u32)f2h(r0[0]) | ((u32)f2h(r0[1]) << 16);
      v.y = (u32)f2h(r0[2]) | ((u32)f2h(r0[3]) << 16);
      v.z = (u32)f2h(r1[0]) | ((u32)f2h(r1[1]) << 16);
      v.w = (u32)f2h(r1[2]) | ((u32)f2h(r1[3]) << 16);
      *(u32x4*)(vp + (e << 3)) = v;
    }
  }
  {
    const int j = tid & 31, s = tid >> 5;
    float acc = 0.f;
#pragma unroll 8
    for (int k = 0; k < 32; ++k)
      acc += g[(s << 5) + k] * Xs[((s << 5) + k) * 37 + j];
    Ps[j * 9 + s] = acc;
  }
  __syncthreads();
  if (tid < 32) {
    float a = 0.f;
#pragma unroll
    for (int s = 0; s < 8; ++s) a += Ps[tid * 9 + s];
    r2[(b << 12) + j0 + tid] = a;
  }
}

// K3: QT=16, 128-thread blocks (2 waves, j-split), grid 1024.
// Barrier-free main loop: each wave stages ITS OWN K half (rows 16h..16h+15),
// counted-vmcnt pipeline (steady state vmcnt(8)/vmcnt(9), no drain),
// V + r2 prefetched one tile ahead into registers.
__launch_bounds__(128, 2)
__global__ void k_attn(const float* __restrict__ x1, const ush* __restrict__ kimg,
                       const ush* __restrict__ vimg, const float* __restrict__ M,
                       const float* __restrict__ r2, float* __restrict__ out) {
  extern __shared__ ush lds[];
  const int tid  = threadIdx.x;
  const int lane = tid & 63;
  const int h    = tid >> 6;       // wave = j-group
  const int g    = lane >> 4;
  const int lq   = lane & 15;

  int bid = (int)blockIdx.x;
  bid = (bid & 7) * 128 + (bid >> 3);       // bijective XCD swizzle (1024 = 8*128)
  const int b  = bid >> 8;
  const int i0 = (bid & 255) << 4;

  const float* x1b = x1 + ((size_t)b << 20);

  // ---- Q-prep (VALU f32): x1f @0 (18KB), Qhi @ byte 18432 (8KB) ----
  float* x1f = (float*)lds;                 // [256][18] f32
  ush* Qhi = lds + 9216;                    // [16][256] halves
  {
    const int jf = tid & 3, c0 = tid >> 2;
#pragma unroll
    for (int m = 0; m < 8; ++m) {
      int c = c0 + (m << 5);
      float4 v = *(const float4*)(x1b + ((size_t)c << 12) + i0 + (jf << 2));
      *(float4*)(x1f + c * 18 + (jf << 2)) = v;
    }
  }
  __syncthreads();
  {
    const int tc = tid & 63, iq = tid >> 6;
    float acc[4][8];
#pragma unroll
    for (int q = 0; q < 4; ++q)
#pragma unroll
      for (int e = 0; e < 8; ++e) acc[q][e] = 0.f;
#pragma unroll 4
    for (int c = 0; c < CC; ++c) {
      float4 mv = *(const float4*)(M + c * CC + (tc << 2));
      float4 xa = *(const float4*)(x1f + c * 18 + (iq << 3));
      float4 xb = *(const float4*)(x1f + c * 18 + (iq << 3) + 4);
      float xs[8] = {xa.x, xa.y, xa.z, xa.w, xb.x, xb.y, xb.z, xb.w};
#pragma unroll
      for (int e = 0; e < 8; ++e) {
        acc[0][e] += mv.x * xs[e];
        acc[1][e] += mv.y * xs[e];
        acc[2][e] += mv.z * xs[e];
        acc[3][e] += mv.w * xs[e];
      }
    }
    __syncthreads();
#pragma unroll
    for (int e = 0; e < 8; ++e) {
      int i = (iq << 3) + e;
      u32 h0 = (u32)f2h(acc[0][e]) | ((u32)f2h(acc[1][e]) << 16);
      u32 h1 = (u32)f2h(acc[2][e]) | ((u32)f2h(acc[3][e]) << 16);
      u32x2 hw; hw.x = h0; hw.y = h1;
      *(u32x2*)(Qhi + (i << 8) + (tc << 2)) = hw;
    }
  }
  __syncthreads();

  // ---- preload Q fragments ----
  Frag8 QBh[8];
  {
    const int qoff = lq << 8;
#pragma unroll
    for (int cs = 0; cs < 8; ++cs)
      QBh[cs].u4 = *(const u32x4*)(Qhi + qoff + (cs << 5) + (g << 3));
  }
  __syncthreads();

  // ---- main flash loop (barrier-free, per-wave pipelines) ----
  f32x4 vacc[16];
#pragma unroll
  for (int ct = 0; ct < 16; ++ct) vacc[ct] = (f32x4){0.f, 0.f, 0.f, 0.f};
  float m_run = -3.0e38f, l_run = 0.f;

  const int jrow  = (h << 4) + lq;
  const int sx    = lq & 7;
  const int koff  = jrow << 8;              // halves
  const int wbase = h << 9;                 // this wave's 512 16B-slots half
  const float* r2p = r2 + (b << 12) + (h << 4) + (g << 2);
  const size_t bt = (size_t)(b << 7);
  const ush* vbase = vimg + (bt << 13) + (h << 9) + (g << 7) + (lq << 3);

  Frag8 Vd[8];
  float4 r2a, r2b;

  // prologue: K(0) half-DMA, V(0), r2(0); wait K(0) only.
  asm volatile("s_waitcnt vmcnt(0)" ::: "memory");
  __builtin_amdgcn_sched_barrier(0);
  {
    const ush* gk = kimg + (bt << 13);
#pragma unroll
    for (int m = 0; m < 8; ++m) {
      int idx = wbase + lane + (m << 6);
      gload16(gk + (idx << 3), lds + (idx << 3));
    }
#pragma unroll
    for (int m = 0; m < 8; ++m)
      Vd[m].u4 = *(const u32x4*)(vbase + (m << 10));
    r2a = *(const float4*)(r2p);
  }
  __builtin_amdgcn_sched_barrier(0);
  asm volatile("s_waitcnt vmcnt(9)" ::: "memory");
  __builtin_amdgcn_sched_barrier(0);

  auto body = [&](int t, float4& r2c, float4& r2n) {
    const int cur = (t & 1) << 13;
    // issue K-DMA(t+1) for this wave's half
    if (t + 1 < 128) {
      const int nxt = cur ^ 8192;
      const ush* gk = kimg + ((bt + t + 1) << 13);
#pragma unroll
      for (int m = 0; m < 8; ++m) {
        int idx = wbase + lane + (m << 6);
        gload16(gk + (idx << 3), lds + nxt + (idx << 3));
      }
    }
    __builtin_amdgcn_sched_barrier(0);
    const ush* kb = lds + cur;

    // S^T = K·Q: 8 MFMA, 4 independent chains
    f32x4 a1 = {0.f,0.f,0.f,0.f}, a2 = {0.f,0.f,0.f,0.f};
    f32x4 a3 = {0.f,0.f,0.f,0.f}, a4 = {0.f,0.f,0.f,0.f};
#pragma unroll
    for (int cs = 0; cs < 8; ++cs) {
      int st = ((cs << 2) + g) ^ sx;
      Frag8 Ah; Ah.u4 = *(const u32x4*)(kb + koff + (st << 3));
      if ((cs & 3) == 0)      a1 = MFMA32(Ah.f, QBh[cs].f, a1);
      else if ((cs & 3) == 1) a2 = MFMA32(Ah.f, QBh[cs].f, a2);
      else if ((cs & 3) == 2) a3 = MFMA32(Ah.f, QBh[cs].f, a3);
      else                    a4 = MFMA32(Ah.f, QBh[cs].f, a4);
    }

    // wait V(t)+r2(t) (K(t+1)'s 8 DMAs stay in flight)
    if (t + 1 < 128) {
      asm volatile("s_waitcnt vmcnt(8)" ::: "memory");
    } else {
      asm volatile("s_waitcnt vmcnt(0)" ::: "memory");
    }
    __builtin_amdgcn_sched_barrier(0);

    // online softmax (rows i = lq; j = 32t + 16h + 4g + r)
    float s0 = a1[0] + a2[0] + a3[0] + a4[0] + r2c.x;
    float s1 = a1[1] + a2[1] + a3[1] + a4[1] + r2c.y;
    float s2 = a1[2] + a2[2] + a3[2] + a4[2] + r2c.z;
    float s3 = a1[3] + a2[3] + a3[3] + a4[3] + r2c.w;
    float mx = fmaxf(fmaxf(s0, s1), fmaxf(s2, s3));
    mx = fmaxf(mx, __shfl_xor(mx, 16));
    mx = fmaxf(mx, __shfl_xor(mx, 32));
    float mn = fmaxf(m_run, mx);
    int stb = (mn == m_run) ? 1 : 0;
    float scl = __expf(m_run - mn);
    float p0 = __expf(s0 - mn), p1 = __expf(s1 - mn);
    float p2 = __expf(s2 - mn), p3 = __expf(s3 - mn);
    float rs = p0 + p1 + p2 + p3;
    rs += __shfl_xor(rs, 16);
    rs += __shfl_xor(rs, 32);
    l_run = l_run * scl + rs;
    m_run = mn;

    Frag4 Pf;
    Pf.u2.x = pkrtz(p0, p1);
    Pf.u2.y = pkrtz(p2, p3);

    if (!__all(stb)) {
#pragma unroll
      for (int ct = 0; ct < 16; ++ct) {
        vacc[ct][0] *= scl; vacc[ct][1] *= scl;
        vacc[ct][2] *= scl; vacc[ct][3] *= scl;
      }
    }
#pragma unroll
    for (int m = 0; m < 8; ++m) {
      Frag4 Va, Vb;
      Va.u2.x = Vd[m].u4.x; Va.u2.y = Vd[m].u4.y;     // ct = 2m
      Vb.u2.x = Vd[m].u4.z; Vb.u2.y = Vd[m].u4.w;     // ct = 2m+1
      vacc[2 * m]     = MFMA16(Va.f, Pf.f, vacc[2 * m]);
      vacc[2 * m + 1] = MFMA16(Vb.f, Pf.f, vacc[2 * m + 1]);
    }

    if (t + 1 < 128) {
      // prefetch V(t+1), r2(t+1); then wait K(t+1) (V/r2 stay in flight)
      const ush* vt_ = vbase + ((size_t)(t + 1) << 13);
#pragma unroll
      for (int m = 0; m < 8; ++m)
        Vd[m].u4 = *(const u32x4*)(vt_ + (m << 10));
      r2n = *(const float4*)(r2p + ((t + 1) << 5));
      __builtin_amdgcn_sched_barrier(0);
      asm volatile("s_waitcnt vmcnt(9)" ::: "memory");
      __builtin_amdgcn_sched_barrier(0);
    }
  };

  for (int tt = 0; tt < 128; tt += 2) {
    body(tt,     r2a, r2b);
    body(tt + 1, r2b, r2a);
  }

  // ---- merge j-halves, normalize, store ----
  __syncthreads();
  float* Cmb = (float*)lds;                 // [256][17] f32 = 17408B
  float* Msm = (float*)(lds + 8704);        // byte 17408
  float* Lsm = Msm + 32;
  if (g == 0) {
    Msm[h * 16 + lq] = m_run;
    Lsm[h * 16 + lq] = l_run;
  }
  __syncthreads();
  float mo  = Msm[(1 - h) * 16 + lq];
  float lo2 = Lsm[(1 - h) * 16 + lq];
  float mt    = fmaxf(m_run, mo);
  float aSelf = __expf(m_run - mt);
  float l_tot = l_run * aSelf + lo2 * __expf(mo - mt);

  if (h == 0) {
#pragma unroll
    for (int ct = 0; ct < 16; ++ct)
#pragma unroll
      for (int r = 0; r < 4; ++r)
        Cmb[((ct << 4) + (g << 2) + r) * RSC + lq] = vacc[ct][r] * aSelf;
  }
  __syncthreads();
  if (h == 1) {
    float inv = 1.f / l_tot;
    float* ob = out + ((size_t)b << 20) + i0 + lq;
#pragma unroll
    for (int ct = 0; ct < 16; ++ct)
#pragma unroll
      for (int r = 0; r < 4; ++r) {
        int c = (ct << 4) + (g << 2) + r;
        ob[(size_t)c << 12] = (vacc[ct][r] * aSelf + Cmb[c * RSC + lq]) * inv;
      }
  }
}

extern "C" void kernel_launch(void* const* d_in, const int* in_sizes, int n_in,
                              void* d_out, int out_size, void* d_ws, size_t ws_size,
                              hipStream_t stream) {
  const float* x1 = (const float*)d_in[0];
  const float* x2 = (const float*)d_in[1];
  const float* w1 = (const float*)d_in[2];
  const float* b1 = (const float*)d_in[3];
  const float* w2 = (const float*)d_in[4];
  // b2 (d_in[5]) contributes only row-constant energy terms -> cancels in softmax.

  float* M  = (float*)d_ws;            // 256KB
  float* g  = M + 65536;
  float* r2 = g + 256;                 // 64KB
  ush* kimg = (ush*)(r2 + 16384);      // 8MB, per-tile 16KB LDS byte-images
  ush* vimg = kimg + 4194304;          // 8MB, per-tile PV-fragment-ordered fp16
  float* outp = (float*)d_out;

  const int LDS_BYTES = 32768;
  (void)hipFuncSetAttribute((const void*)k_attn,
                            hipFuncAttributeMaxDynamicSharedMemorySize, LDS_BYTES);

  k_prep<<<CC, 256, 0, stream>>>(w1, w2, b1, M, g);
  k_cvt<<<BB * (NN / 32), 256, 0, stream>>>(x2, g, kimg, vimg, r2);
  k_attn<<<BB * (NN / 16), 128, LDS_BYTES, stream>>>(x1, kimg, vimg, M, r2, outp);
  (void)in_sizes; (void)n_in; (void)out_size; (void)ws_size;
}

// Round 11
// 261.488 us; speedup vs baseline: 1.3794x; 1.0383x over previous
//
#include <hip/hip_runtime.h>

typedef _Float16 f16;
typedef _Float16 f16x8 __attribute__((ext_vector_type(8)));
typedef _Float16 f16x4 __attribute__((ext_vector_type(4)));
typedef float    f32x4 __attribute__((ext_vector_type(4)));
typedef unsigned int u32;
typedef u32 u32x2 __attribute__((ext_vector_type(2)));
typedef u32 u32x4 __attribute__((ext_vector_type(4)));
typedef unsigned short ush;

#define CC 256
#define NN 4096
#define BB 4
#define RSC 17          // combine buffer stride (f32)

union Frag8 { u32x4 u4; f16x8 f; };
union Frag4 { u32x2 u2; f16x4 f; };

static __device__ __forceinline__ u32 pkrtz(float a, float b) {
  auto t = __builtin_amdgcn_cvt_pkrtz(a, b);
  return __builtin_bit_cast(u32, t);
}
static __device__ __forceinline__ ush f2h(float x) {   // RNE
  f16 h = (f16)x;
  return __builtin_bit_cast(ush, h);
}

static __device__ __forceinline__ void gload16(const ush* g, ush* l) {
  __builtin_amdgcn_global_load_lds(
      (const __attribute__((address_space(1))) u32*)g,
      (__attribute__((address_space(3))) u32*)l, 16, 0, 0);
}

#define MFMA32(A, B, C) __builtin_amdgcn_mfma_f32_16x16x32_f16((A), (B), (C), 0, 0, 0)
#define MFMA16(A, B, C) __builtin_amdgcn_mfma_f32_16x16x16f16((A), (B), (C), 0, 0, 0)

// K1: M[c][cp] = sum_o w1[o,c]*w2[o,cp] ; g[cp] = sum_o b1[o]*w2[o,cp]
__global__ void k_prep(const float* __restrict__ w1, const float* __restrict__ w2,
                       const float* __restrict__ b1, float* __restrict__ M,
                       float* __restrict__ g) {
  const int c  = blockIdx.x;
  const int cp = threadIdx.x;
  float acc = 0.f;
#pragma unroll 8
  for (int o = 0; o < CC; ++o)
    acc += w1[o * CC + c] * w2[o * CC + cp];
  M[c * CC + cp] = acc;
  if (c == 0) {
    float ga = 0.f;
    for (int o = 0; o < CC; ++o)
      ga += b1[o] * w2[o * CC + cp];
    g[cp] = ga;
  }
}

// K-cvt: x2 tile -> kimg (swizzled [j][c] LDS byte-image) + vimg (PV-fragment
// order) + r2[b,j] = sum_c g[c]*x2[b,c,j].   (all fp16 RNE)
// K image row j (512B): 16B slot st holds halves c=8s..8s+7 with s = st^(j&7).
__global__ void k_cvt(const float* __restrict__ x2, const float* __restrict__ g,
                      ush* __restrict__ kimg, ush* __restrict__ vimg,
                      float* __restrict__ r2) {
  __shared__ float Xs[256 * 37];
  __shared__ float Ps[32 * 9];
  const int tid = threadIdx.x;
  const int b   = blockIdx.x >> 7;
  const int jt  = blockIdx.x & 127;
  const int j0  = jt << 5;
  const float* x2b = x2 + ((size_t)b << 20);
  {
    const int jf = tid & 7, c0 = tid >> 3;
#pragma unroll
    for (int m = 0; m < 8; ++m) {
      int c = c0 + (m << 5);
      float4 v = *(const float4*)(x2b + ((size_t)c << 12) + j0 + (jf << 2));
      *(float4*)(Xs + c * 37 + (jf << 2)) = v;
    }
  }
  __syncthreads();
  const size_t tile = ((size_t)blockIdx.x) << 13;   // halves
  {
    ush* kp = kimg + tile;
#pragma unroll
    for (int m = 0; m < 4; ++m) {
      int idx = tid + (m << 8);
      int j = idx >> 5, st = idx & 31;
      int s = st ^ (j & 7);
      u32 hw[4];
#pragma unroll
      for (int k = 0; k < 4; ++k) {
        float a  = Xs[(8 * s + 2 * k) * 37 + j];
        float c2 = Xs[(8 * s + 2 * k + 1) * 37 + j];
        hw[k] = (u32)f2h(a) | ((u32)f2h(c2) << 16);
      }
      u32x4 v; v.x = hw[0]; v.y = hw[1]; v.z = hw[2]; v.w = hw[3];
      *(u32x4*)(kp + (idx << 3)) = v;
    }
  }
  {
    ush* vp = vimg + tile;
#pragma unroll
    for (int mm = 0; mm < 4; ++mm) {
      int e = tid + (mm << 8);
      int lqe = e & 15, ge = (e >> 4) & 3, he = (e >> 6) & 1, me = e >> 7;
      int c0 = lqe + (me << 5);
      int q0 = (he << 4) + (ge << 2);
      const float* r0 = Xs + c0 * 37 + q0;
      const float* r1 = Xs + (c0 + 16) * 37 + q0;
      u32x4 v;
      v.x = (u32)f2h(r0[0]) | ((u32)f2h(r0[1]) << 16);
      v.y = (u32)f2h(r0[2]) | ((u32)f2h(r0[3]) << 16);
      v.z = (u32)f2h(r1[0]) | ((u32)f2h(r1[1]) << 16);
      v.w = (u32)f2h(r1[2]) | ((u32)f2h(r1[3]) << 16);
      *(u32x4*)(vp + (e << 3)) = v;
    }
  }
  {
    const int j = tid & 31, s = tid >> 5;
    float acc = 0.f;
#pragma unroll 8
    for (int k = 0; k < 32; ++k)
      acc += g[(s << 5) + k] * Xs[((s << 5) + k) * 37 + j];
    Ps[j * 9 + s] = acc;
  }
  __syncthreads();
  if (tid < 32) {
    float a = 0.f;
#pragma unroll
    for (int s = 0; s < 8; ++s) a += Ps[tid * 9 + s];
    r2[(b << 12) + j0 + tid] = a;
  }
}

// K3: QT=64, 512-thread blocks (8 waves = 4 i-groups x 2 j-groups), grid 256.
// K AND V DMA'd into 32KB dbuf LDS (shared by all i-group waves -> 4x less
// global traffic). Per tile: issue DMA(t+1) + r2(t+1), S, softmax, PV,
// vmcnt(0)+barrier (drains loads issued a full tile earlier).
__launch_bounds__(512, 2)
__global__ void k_attn(const float* __restrict__ x1, const ush* __restrict__ kimg,
                       const ush* __restrict__ vimg, const float* __restrict__ M,
                       const float* __restrict__ r2, float* __restrict__ out) {
  extern __shared__ ush lds[];
  const int tid  = threadIdx.x;
  const int lane = tid & 63;
  const int w    = tid >> 6;
  const int p    = w >> 1;         // i-group 0..3
  const int h    = w & 1;          // j-group
  const int g    = lane >> 4;
  const int lq   = lane & 15;

  int bid = (int)blockIdx.x;
  bid = (bid & 7) * 32 + (bid >> 3);        // bijective XCD swizzle (256 = 8*32)
  const int b  = bid >> 6;
  const int i0 = (bid & 63) << 6;

  const float* x1b = x1 + ((size_t)b << 20);

  // ---- Q-prep (VALU f32, two 32-i passes); x1f @0, Qhi @ byte 33792 ----
  float* x1f = (float*)lds;                 // [256][33] f32 = 33792B
  ush* Qhi = lds + 16896;                   // [64][256] halves = 32KB
  for (int ih = 0; ih < 2; ++ih) {
    {
      const int jf = tid & 7, c0 = tid >> 3;
#pragma unroll
      for (int m = 0; m < 4; ++m) {
        int c = c0 + (m << 6);
        float4 v = *(const float4*)(x1b + ((size_t)c << 12) + i0 + (ih << 5) + (jf << 2));
        *(float4*)(x1f + c * 33 + (jf << 2)) = v;
      }
    }
    __syncthreads();
    {
      const int tc = tid & 63, iq = tid >> 6;    // i = 32ih + 4iq + e
      float acc[4][4];
#pragma unroll
      for (int q = 0; q < 4; ++q)
#pragma unroll
        for (int e = 0; e < 4; ++e) acc[q][e] = 0.f;
#pragma unroll 4
      for (int c = 0; c < CC; ++c) {
        float4 mv = *(const float4*)(M + c * CC + (tc << 2));
        float4 xs = *(const float4*)(x1f + c * 33 + (iq << 2));
        float xv[4] = {xs.x, xs.y, xs.z, xs.w};
#pragma unroll
        for (int e = 0; e < 4; ++e) {
          acc[0][e] += mv.x * xv[e];
          acc[1][e] += mv.y * xv[e];
          acc[2][e] += mv.z * xv[e];
          acc[3][e] += mv.w * xv[e];
        }
      }
      __syncthreads();
#pragma unroll
      for (int e = 0; e < 4; ++e) {
        int i = (ih << 5) + (iq << 2) + e;
        u32 h0 = (u32)f2h(acc[0][e]) | ((u32)f2h(acc[1][e]) << 16);
        u32 h1 = (u32)f2h(acc[2][e]) | ((u32)f2h(acc[3][e]) << 16);
        u32x2 hw; hw.x = h0; hw.y = h1;
        *(u32x2*)(Qhi + (i << 8) + (tc << 2)) = hw;
      }
    }
    __syncthreads();
  }

  // ---- preload Q fragments (wave (p,h): Q rows 16p..16p+15) ----
  Frag8 QBh[8];
  {
    const int qoff = ((p << 4) + lq) << 8;
#pragma unroll
    for (int cs = 0; cs < 8; ++cs)
      QBh[cs].u4 = *(const u32x4*)(Qhi + qoff + (cs << 5) + (g << 3));
  }
  __syncthreads();

  // ---- main flash loop ----
  f32x4 vacc[16];
#pragma unroll
  for (int ct = 0; ct < 16; ++ct) vacc[ct] = (f32x4){0.f, 0.f, 0.f, 0.f};
  float m_run = -3.0e38f, l_run = 0.f;

  const int sx    = lq & 7;
  const int koff  = (((h << 4) + lq) << 8);           // K row (halves)
  const int vslt0 = (h << 6) + (g << 4) + lq;         // V slot base (16B slots)
  const float* r2p = r2 + (b << 12) + (h << 4) + (g << 2);
  const size_t bt = (size_t)(b << 7);

  float4 r2a, r2b;

  // prologue: K(0)+V(0) DMA into buf0, r2(0); full drain + barrier.
  {
    const ush* gk = kimg + (bt << 13);
    const ush* gv = vimg + (bt << 13);
    gload16(gk + ((size_t)tid << 3),         lds + (tid << 3));
    gload16(gk + ((size_t)(tid + 512) << 3), lds + ((tid + 512) << 3));
    gload16(gv + ((size_t)tid << 3),         lds + 8192 + (tid << 3));
    gload16(gv + ((size_t)(tid + 512) << 3), lds + 8192 + ((tid + 512) << 3));
    r2a = *(const float4*)(r2p);
  }
  asm volatile("s_waitcnt vmcnt(0)" ::: "memory");
  __builtin_amdgcn_sched_barrier(0);
  __builtin_amdgcn_s_barrier();

  auto body = [&](int t, float4& r2c, float4& r2n) {
    const int cur = (t & 1) << 14;           // halves: 0 / 16384 (32KB buffers)
    // issue K+V DMA(t+1) into other buffer + r2(t+1)
    if (t + 1 < 128) {
      const int nxt = cur ^ 16384;
      const ush* gk = kimg + ((bt + t + 1) << 13);
      const ush* gv = vimg + ((bt + t + 1) << 13);
      gload16(gk + ((size_t)tid << 3),         lds + nxt + (tid << 3));
      gload16(gk + ((size_t)(tid + 512) << 3), lds + nxt + ((tid + 512) << 3));
      gload16(gv + ((size_t)tid << 3),         lds + nxt + 8192 + (tid << 3));
      gload16(gv + ((size_t)(tid + 512) << 3), lds + nxt + 8192 + ((tid + 512) << 3));
      r2n = *(const float4*)(r2p + ((t + 1) << 5));
    }
    __builtin_amdgcn_sched_barrier(0);
    const ush* kb = lds + cur;
    const ush* vb = lds + cur + 8192;

    // S^T = K·Q: 8 MFMA, 4 independent chains
    f32x4 a1 = {0.f,0.f,0.f,0.f}, a2 = {0.f,0.f,0.f,0.f};
    f32x4 a3 = {0.f,0.f,0.f,0.f}, a4 = {0.f,0.f,0.f,0.f};
#pragma unroll
    for (int cs = 0; cs < 8; ++cs) {
      int st = ((cs << 2) + g) ^ sx;
      Frag8 Ah; Ah.u4 = *(const u32x4*)(kb + koff + (st << 3));
      if ((cs & 3) == 0)      a1 = MFMA32(Ah.f, QBh[cs].f, a1);
      else if ((cs & 3) == 1) a2 = MFMA32(Ah.f, QBh[cs].f, a2);
      else if ((cs & 3) == 2) a3 = MFMA32(Ah.f, QBh[cs].f, a3);
      else                    a4 = MFMA32(Ah.f, QBh[cs].f, a4);
    }

    // online softmax (rows i = 16p+lq; j = 32t + 16h + 4g + r)
    float s0 = a1[0] + a2[0] + a3[0] + a4[0] + r2c.x;
    float s1 = a1[1] + a2[1] + a3[1] + a4[1] + r2c.y;
    float s2 = a1[2] + a2[2] + a3[2] + a4[2] + r2c.z;
    float s3 = a1[3] + a2[3] + a3[3] + a4[3] + r2c.w;
    float mx = fmaxf(fmaxf(s0, s1), fmaxf(s2, s3));
    mx = fmaxf(mx, __shfl_xor(mx, 16));
    mx = fmaxf(mx, __shfl_xor(mx, 32));
    float mn = fmaxf(m_run, mx);
    int stb = (mn == m_run) ? 1 : 0;
    float scl = __expf(m_run - mn);
    float p0 = __expf(s0 - mn), p1 = __expf(s1 - mn);
    float p2 = __expf(s2 - mn), p3 = __expf(s3 - mn);
    float rs = p0 + p1 + p2 + p3;
    rs += __shfl_xor(rs, 16);
    rs += __shfl_xor(rs, 32);
    l_run = l_run * scl + rs;
    m_run = mn;

    Frag4 Pf;
    Pf.u2.x = pkrtz(p0, p1);
    Pf.u2.y = pkrtz(p2, p3);

    if (!__all(stb)) {
#pragma unroll
      for (int ct = 0; ct < 16; ++ct) {
        vacc[ct][0] *= scl; vacc[ct][1] *= scl;
        vacc[ct][2] *= scl; vacc[ct][3] *= scl;
      }
    }
    // PV: V from LDS, b128 per m (slots m*128 + h*64 + g*16 + lq)
#pragma unroll
    for (int m = 0; m < 8; ++m) {
      Frag8 Vd;
      Vd.u4 = *(const u32x4*)(vb + ((vslt0 + (m << 7)) << 3));
      Frag4 Va, Vb2;
      Va.u2.x  = Vd.u4.x; Va.u2.y  = Vd.u4.y;     // ct = 2m
      Vb2.u2.x = Vd.u4.z; Vb2.u2.y = Vd.u4.w;     // ct = 2m+1
      vacc[2 * m]     = MFMA16(Va.f,  Pf.f, vacc[2 * m]);
      vacc[2 * m + 1] = MFMA16(Vb2.f, Pf.f, vacc[2 * m + 1]);
    }

    // drain this tile's prefetch (issued ~a full tile ago) + barrier
    if (t + 1 < 128) {
      asm volatile("s_waitcnt vmcnt(0)" ::: "memory");
      __builtin_amdgcn_sched_barrier(0);
      __builtin_amdgcn_s_barrier();
    }
  };

  for (int tt = 0; tt < 128; tt += 2) {
    body(tt,     r2a, r2b);
    body(tt + 1, r2b, r2a);
  }

  // ---- merge j-halves, normalize, store ----
  __syncthreads();
  float* Cmb = (float*)lds;                 // [4][256][17] f32 = 69632B
  float* Msm = (float*)(lds + 34816);       // byte 69632: [4][2][16]
  float* Lsm = Msm + 128;
  if (g == 0) {
    Msm[p * 32 + h * 16 + lq] = m_run;
    Lsm[p * 32 + h * 16 + lq] = l_run;
  }
  __syncthreads();
  float mo  = Msm[p * 32 + (1 - h) * 16 + lq];
  float lo2 = Lsm[p * 32 + (1 - h) * 16 + lq];
  float mt    = fmaxf(m_run, mo);
  float aSelf = __expf(m_run - mt);
  float l_tot = l_run * aSelf + lo2 * __expf(mo - mt);

  if (h == 0) {
    float* cb_ = Cmb + p * (CC * RSC);
#pragma unroll
    for (int ct = 0; ct < 16; ++ct)
#pragma unroll
      for (int r = 0; r < 4; ++r)
        cb_[((ct << 4) + (g << 2) + r) * RSC + lq] = vacc[ct][r] * aSelf;
  }
  __syncthreads();
  if (h == 1) {
    const float* cb_ = Cmb + p * (CC * RSC);
    float inv = 1.f / l_tot;
    float* ob = out + ((size_t)b << 20) + i0 + (p << 4) + lq;
#pragma unroll
    for (int ct = 0; ct < 16; ++ct)
#pragma unroll
      for (int r = 0; r < 4; ++r) {
        int c = (ct << 4) + (g << 2) + r;
        ob[(size_t)c << 12] = (vacc[ct][r] * aSelf + cb_[c * RSC + lq]) * inv;
      }
  }
}

extern "C" void kernel_launch(void* const* d_in, const int* in_sizes, int n_in,
                              void* d_out, int out_size, void* d_ws, size_t ws_size,
                              hipStream_t stream) {
  const float* x1 = (const float*)d_in[0];
  const float* x2 = (const float*)d_in[1];
  const float* w1 = (const float*)d_in[2];
  const float* b1 = (const float*)d_in[3];
  const float* w2 = (const float*)d_in[4];
  // b2 (d_in[5]) contributes only row-constant energy terms -> cancels in softmax.

  float* M  = (float*)d_ws;            // 256KB
  float* g  = M + 65536;
  float* r2 = g + 256;                 // 64KB
  ush* kimg = (ush*)(r2 + 16384);      // 8MB, per-tile 16KB LDS byte-images
  ush* vimg = kimg + 4194304;          // 8MB, per-tile PV-fragment-ordered fp16
  float* outp = (float*)d_out;

  const int LDS_BYTES = 70656;
  (void)hipFuncSetAttribute((const void*)k_attn,
                            hipFuncAttributeMaxDynamicSharedMemorySize, LDS_BYTES);

  k_prep<<<CC, 256, 0, stream>>>(w1, w2, b1, M, g);
  k_cvt<<<BB * (NN / 32), 256, 0, stream>>>(x2, g, kimg, vimg, r2);
  k_attn<<<BB * (NN / 64), 512, LDS_BYTES, stream>>>(x1, kimg, vimg, M, r2, outp);
  (void)in_sizes; (void)n_in; (void)out_size; (void)ws_size;
}